// Round 1
// baseline (666.158 us; speedup 1.0000x reference)
//
#include <hip/hip_runtime.h>
#include <hip/hip_bf16.h>

// Problem constants (from reference): N=32, T=2048, D_ENC=D_DEC=U=1024
#define NB 32
#define TD 2048
#define DIM 1024

typedef _Float16 v8h __attribute__((ext_vector_type(8)));
typedef _Float16 v4h __attribute__((ext_vector_type(4)));
typedef float    v4f __attribute__((ext_vector_type(4)));

__device__ __forceinline__ float ftanh(float x) {
    // tanh via exp2-backed __expf; clamp so (e-1)/(e+1) never hits inf/inf
    x = fminf(15.f, fmaxf(-15.f, x));
    float e = __expf(2.f * x);
    return (e - 1.f) / (e + 1.f);
}

// K1: pq[n][u] = queries[n] . Wq[u]   (one wave per output, f32)
__global__ __launch_bounds__(256) void pq_kernel(const float* __restrict__ q,
                                                 const float* __restrict__ Wq,
                                                 float* __restrict__ pq) {
    int wid  = blockIdx.x * 4 + (threadIdx.x >> 6);
    int lane = threadIdx.x & 63;
    int n = wid >> 10;
    int u = wid & 1023;
    const float4* qr = (const float4*)(q  + (size_t)n * DIM);
    const float4* wr = (const float4*)(Wq + (size_t)u * DIM);
    float s = 0.f;
#pragma unroll
    for (int j = 0; j < 4; ++j) {
        int i = lane + 64 * j;
        float4 a = qr[i], b = wr[i];
        s += a.x * b.x + a.y * b.y + a.z * b.z + a.w * b.w;
    }
#pragma unroll
    for (int off = 32; off >= 1; off >>= 1) s += __shfl_xor(s, off);
    if (lane == 0) pq[(size_t)n * DIM + u] = s;
}

// K2: fused  weights[r] += sum_u tanh(pq[n][u] + enc[r].Wk[u]) * v[u]
// 128x128 tile f16 MFMA GEMM, inline f32->f16 convert during LDS staging.
// grid = (512 row tiles, 8 u tiles); block-level skip of fully-masked rows.
__global__ __launch_bounds__(256) void gemm_tanh_kernel(
        const float* __restrict__ enc, const float* __restrict__ Wk,
        const float* __restrict__ pq,  const float* __restrict__ v,
        const int* __restrict__ lengths, float* __restrict__ weights) {
    const int bm = blockIdx.x;            // 512 row tiles of 128 (n*T flattened)
    const int bn = blockIdx.y;            // 8 col (u) tiles of 128
    const int rowBase = bm * 128;
    const int n = rowBase >> 11;          // T=2048 divides tile boundaries
    const int tstart = rowBase & 2047;
    if (lengths[n] <= tstart) return;     // whole tile masked -> weights stay 0

    __shared__ _Float16 As[128 * 40];     // 128 rows x BK=32, pad to 40 halves
    __shared__ _Float16 Bs[128 * 40];

    const int tid  = threadIdx.x;
    const int lane = tid & 63;
    const int wv   = tid >> 6;
    const int wm   = wv >> 1, wn = wv & 1;  // 2x2 wave grid, 64x64 per wave
    const int q4   = lane >> 4;             // quad
    const int l16  = lane & 15;

    v4f acc[4][4];
    const v4f vz = {0.f, 0.f, 0.f, 0.f};
#pragma unroll
    for (int i = 0; i < 4; ++i)
#pragma unroll
        for (int j = 0; j < 4; ++j) acc[i][j] = vz;

    const int srow = tid >> 3;        // 0..31
    const int skc  = (tid & 7) * 4;   // 0,4,..,28

    for (int k0 = 0; k0 < DIM; k0 += 32) {
        __syncthreads();
#pragma unroll
        for (int j = 0; j < 4; ++j) {
            int row = j * 32 + srow;
            float4 av = *(const float4*)(enc + (size_t)(rowBase + row) * DIM + k0 + skc);
            v4h ah;
            ah.x = (_Float16)av.x; ah.y = (_Float16)av.y;
            ah.z = (_Float16)av.z; ah.w = (_Float16)av.w;
            *(v4h*)(&As[row * 40 + skc]) = ah;
            float4 bv = *(const float4*)(Wk + (size_t)(bn * 128 + row) * DIM + k0 + skc);
            v4h bh;
            bh.x = (_Float16)bv.x; bh.y = (_Float16)bv.y;
            bh.z = (_Float16)bv.z; bh.w = (_Float16)bv.w;
            *(v4h*)(&Bs[row * 40 + skc]) = bh;
        }
        __syncthreads();

        v8h afr[4], bfr[4];
#pragma unroll
        for (int mt = 0; mt < 4; ++mt)
            afr[mt] = *(const v8h*)(&As[(wm * 64 + mt * 16 + l16) * 40 + q4 * 8]);
#pragma unroll
        for (int nt = 0; nt < 4; ++nt)
            bfr[nt] = *(const v8h*)(&Bs[(wn * 64 + nt * 16 + l16) * 40 + q4 * 8]);
#pragma unroll
        for (int mt = 0; mt < 4; ++mt)
#pragma unroll
            for (int nt = 0; nt < 4; ++nt)
                acc[mt][nt] = __builtin_amdgcn_mfma_f32_16x16x32_f16(
                    afr[mt], bfr[nt], acc[mt][nt], 0, 0, 0);
    }

    // Epilogue: tanh(pq + pk) * v, reduce over this block's 64-u panel per row.
    float pqv[4], vv[4];
#pragma unroll
    for (int nt = 0; nt < 4; ++nt) {
        int ug = bn * 128 + wn * 64 + nt * 16 + l16;
        pqv[nt] = pq[(size_t)n * DIM + ug];
        vv[nt]  = v[ug];
    }
#pragma unroll
    for (int mt = 0; mt < 4; ++mt) {
#pragma unroll
        for (int r = 0; r < 4; ++r) {
            float s = 0.f;
#pragma unroll
            for (int nt = 0; nt < 4; ++nt)
                s += ftanh(acc[mt][nt][r] + pqv[nt]) * vv[nt];
            // C/D layout: col=lane&15, row=q4*4+r -> reduce across the 16 lanes of a quad
            s += __shfl_xor(s, 1);
            s += __shfl_xor(s, 2);
            s += __shfl_xor(s, 4);
            s += __shfl_xor(s, 8);
            if (l16 == 0) {
                int R = rowBase + wm * 64 + mt * 16 + q4 * 4 + r;
                atomicAdd(&weights[R], s);
            }
        }
    }
}

// K3: masked softmax per n-row, in place (weights -> alignments)
__global__ __launch_bounds__(256) void softmax_kernel(float* __restrict__ w,
                                                      const int* __restrict__ lengths) {
    int n = blockIdx.x;
    int len = lengths[n];
    float* row = w + (size_t)n * TD;
    int tid = threadIdx.x;
    float wv[8], ev[8];
    float mx = -INFINITY;
#pragma unroll
    for (int i = 0; i < 8; ++i) {
        int t = tid + i * 256;
        float x = row[t];
        x = (t < len) ? x : -INFINITY;
        wv[i] = x;
        mx = fmaxf(mx, x);
    }
#pragma unroll
    for (int off = 32; off >= 1; off >>= 1) mx = fmaxf(mx, __shfl_xor(mx, off));
    __shared__ float redm[4], reds[4];
    int lane = tid & 63, wvid = tid >> 6;
    if (lane == 0) redm[wvid] = mx;
    __syncthreads();
    mx = fmaxf(fmaxf(redm[0], redm[1]), fmaxf(redm[2], redm[3]));
    float sm = 0.f;
#pragma unroll
    for (int i = 0; i < 8; ++i) { ev[i] = __expf(wv[i] - mx); sm += ev[i]; }
#pragma unroll
    for (int off = 32; off >= 1; off >>= 1) sm += __shfl_xor(sm, off);
    if (lane == 0) reds[wvid] = sm;
    __syncthreads();
    sm = reds[0] + reds[1] + reds[2] + reds[3];
    float inv = 1.f / sm;
#pragma unroll
    for (int i = 0; i < 8; ++i) row[tid + i * 256] = ev[i] * inv;
}

// K4: contexts[n][e] = sum_t align[n][t] * enc[n][t][e]
// grid = (16 t-chunks of 128, 32 n); each thread owns 4 e's; atomic combine.
__global__ __launch_bounds__(256) void ctx_kernel(const float* __restrict__ align,
                                                  const float* __restrict__ enc,
                                                  const int* __restrict__ lengths,
                                                  float* __restrict__ ctx) {
    int n  = blockIdx.y;
    int t0 = blockIdx.x * 128;
    if (lengths[n] <= t0) return;         // fully-masked chunk
    int e = threadIdx.x * 4;
    float4 acc = make_float4(0.f, 0.f, 0.f, 0.f);
    const float* arow = align + (size_t)n * TD;
    const float* erow = enc + (size_t)n * TD * DIM;
    for (int tt = 0; tt < 128; ++tt) {
        int t = t0 + tt;
        float a = arow[t];                // uniform across block
        if (a != 0.f) {
            float4 evv = *(const float4*)(erow + (size_t)t * DIM + e);
            acc.x += a * evv.x; acc.y += a * evv.y;
            acc.z += a * evv.z; acc.w += a * evv.w;
        }
    }
    float* c = ctx + (size_t)n * DIM + e;
    atomicAdd(c + 0, acc.x);
    atomicAdd(c + 1, acc.y);
    atomicAdd(c + 2, acc.z);
    atomicAdd(c + 3, acc.w);
}

extern "C" void kernel_launch(void* const* d_in, const int* in_sizes, int n_in,
                              void* d_out, int out_size, void* d_ws, size_t ws_size,
                              hipStream_t stream) {
    const float* queries = (const float*)d_in[0];   // [32,1,1024]
    const float* enc     = (const float*)d_in[1];   // [32,2048,1024]
    const int*   lengths = (const int*)d_in[2];     // [32]
    const float* v       = (const float*)d_in[3];   // [1024]
    const float* Wq      = (const float*)d_in[4];   // [1024,1024]
    const float* Wk      = (const float*)d_in[5];   // [1024,1024]

    float* out = (float*)d_out;
    float* ctx = out;                // [32,1024]  (also temp home of pq)
    float* alg = out + NB * DIM;     // [32,2048]  (weights -> alignments in place)
    float* pq  = ctx;                // pq fully consumed before ctx memset below
    (void)d_ws; (void)ws_size; (void)in_sizes; (void)n_in; (void)out_size;

    // zero pre-softmax weights (atomic accumulation target)
    hipMemsetAsync(alg, 0, (size_t)NB * TD * sizeof(float), stream);
    pq_kernel<<<NB * DIM / 4, 256, 0, stream>>>(queries, Wq, pq);
    dim3 g2(512, 8);
    gemm_tanh_kernel<<<g2, 256, 0, stream>>>(enc, Wk, pq, v, lengths, alg);
    softmax_kernel<<<NB, 256, 0, stream>>>(alg, lengths);
    // pq no longer needed; reuse its slot for contexts
    hipMemsetAsync(ctx, 0, (size_t)NB * DIM * sizeof(float), stream);
    ctx_kernel<<<dim3(16, NB), 256, 0, stream>>>(alg, enc, lengths, ctx);
}

// Round 2
// 572.531 us; speedup vs baseline: 1.1635x; 1.1635x over previous
//
#include <hip/hip_runtime.h>
#include <hip/hip_bf16.h>

// Problem constants (from reference): N=32, T=2048, D_ENC=D_DEC=U=1024
#define NB 32
#define TD 2048
#define DIM 1024

typedef _Float16 v8h __attribute__((ext_vector_type(8)));
typedef _Float16 v4h __attribute__((ext_vector_type(4)));
typedef float    v4f __attribute__((ext_vector_type(4)));

__device__ __forceinline__ float ftanh(float x) {
    x = fminf(15.f, fmaxf(-15.f, x));
    float e = __expf(2.f * x);
    return (e - 1.f) / (e + 1.f);
}

__device__ __forceinline__ void gld_lds16(const void* g, void* l) {
    __builtin_amdgcn_global_load_lds(
        (const __attribute__((address_space(1))) unsigned int*)g,
        (__attribute__((address_space(3))) unsigned int*)l, 16, 0, 0);
}

// ---------------- K1: pq[n][u] = queries[n] . Wq[u] ----------------
__global__ __launch_bounds__(256) void pq_kernel(const float* __restrict__ q,
                                                 const float* __restrict__ Wq,
                                                 float* __restrict__ pq) {
    int wid  = blockIdx.x * 4 + (threadIdx.x >> 6);
    int lane = threadIdx.x & 63;
    int n = wid >> 10;
    int u = wid & 1023;
    const float4* qr = (const float4*)(q  + (size_t)n * DIM);
    const float4* wr = (const float4*)(Wq + (size_t)u * DIM);
    float s = 0.f;
#pragma unroll
    for (int j = 0; j < 4; ++j) {
        int i = lane + 64 * j;
        float4 a = qr[i], b = wr[i];
        s += a.x * b.x + a.y * b.y + a.z * b.z + a.w * b.w;
    }
#pragma unroll
    for (int off = 32; off >= 1; off >>= 1) s += __shfl_xor(s, off);
    if (lane == 0) pq[(size_t)n * DIM + u] = s;
}

// ---------------- K1b: f32 -> f16 conversion into workspace ----------------
// blocks 0..32767: enc rows (2 rows each, skip masked rows)
// blocks 32768..33279: Wk rows (2 rows each)
__global__ __launch_bounds__(256) void cvt_kernel(const float* __restrict__ enc,
                                                  const float* __restrict__ Wk,
                                                  const int* __restrict__ lengths,
                                                  _Float16* __restrict__ ench,
                                                  _Float16* __restrict__ wkh) {
    int local = threadIdx.x * 8;              // 0..2047 within the 2-row pair
    int rsub  = local >> 10;                  // 0 or 1
    int col   = local & 1023;
    const float* src;
    _Float16* dst;
    size_t row;
    if (blockIdx.x < 32768) {
        row = (size_t)blockIdx.x * 2 + rsub;  // enc row in [0, 65536)
        int n = (int)(row >> 11), t = (int)(row & 2047);
        if (t >= lengths[n]) return;          // masked row: never read downstream
        src = enc; dst = ench;
    } else {
        row = (size_t)(blockIdx.x - 32768) * 2 + rsub;  // Wk row in [0,1024)
        src = Wk; dst = wkh;
    }
    const float4* s = (const float4*)(src + row * DIM + col);
    float4 a = s[0], b = s[1];
    v8h h;
    h[0] = (_Float16)a.x; h[1] = (_Float16)a.y; h[2] = (_Float16)a.z; h[3] = (_Float16)a.w;
    h[4] = (_Float16)b.x; h[5] = (_Float16)b.y; h[6] = (_Float16)b.z; h[7] = (_Float16)b.w;
    *(v8h*)(dst + row * DIM + col) = h;
}

// ---------------- K2 (fast): f16 MFMA GEMM with global_load_lds ----------------
// weights[r] += sum_u tanh(pq[n][u] + enc[r].Wk[u]) * v[u]
// 128x128 tile, BK=32, m97-style async staging. grid = (512, 8).
__global__ __launch_bounds__(256) void gemm_tanh_h(
        const _Float16* __restrict__ ench, const _Float16* __restrict__ wkh,
        const float* __restrict__ pq, const float* __restrict__ v,
        const int* __restrict__ lengths, float* __restrict__ weights) {
    const int bm = blockIdx.x;
    const int bn = blockIdx.y;
    const int rowBase = bm * 128;
    const int n = rowBase >> 11;
    const int tstart = rowBase & 2047;
    if (lengths[n] <= tstart) return;

    __shared__ _Float16 As[128 * 32];   // 8 KB, row-major [row][k], no pad
    __shared__ _Float16 Bs[128 * 32];   // (global_load_lds needs packed lane order)

    const int tid  = threadIdx.x;
    const int lane = tid & 63;
    const int wv   = tid >> 6;
    const int wm   = wv >> 1, wn = wv & 1;   // 2x2 waves, 64x64 each
    const int q4   = lane >> 4;
    const int l16  = lane & 15;

    v4f acc[4][4];
    const v4f vz = {0.f, 0.f, 0.f, 0.f};
#pragma unroll
    for (int i = 0; i < 4; ++i)
#pragma unroll
        for (int j = 0; j < 4; ++j) acc[i][j] = vz;

    // staging: per wave, 2 x 16B per matrix per K-iter.
    // LDS dest (halves): wv*1024 + j*512 (+ lane*8 implicit)
    // source row = wv*32 + j*16 + (lane>>2), kcol = (lane&3)*8
    const int srow = (lane >> 2);
    const int skc  = (lane & 3) * 8;
    const _Float16* Ag = ench + (size_t)rowBase * DIM;
    const _Float16* Bg = wkh + (size_t)bn * 128 * DIM;

    for (int k0 = 0; k0 < DIM; k0 += 32) {
        __syncthreads();
#pragma unroll
        for (int j = 0; j < 2; ++j) {
            int row = wv * 32 + j * 16 + srow;
            gld_lds16(Ag + (size_t)row * DIM + k0 + skc, &As[wv * 1024 + j * 512]);
            gld_lds16(Bg + (size_t)row * DIM + k0 + skc, &Bs[wv * 1024 + j * 512]);
        }
        __syncthreads();

        v8h afr[4], bfr[4];
#pragma unroll
        for (int mt = 0; mt < 4; ++mt)
            afr[mt] = *(const v8h*)(&As[(wm * 64 + mt * 16 + l16) * 32 + q4 * 8]);
#pragma unroll
        for (int nt = 0; nt < 4; ++nt)
            bfr[nt] = *(const v8h*)(&Bs[(wn * 64 + nt * 16 + l16) * 32 + q4 * 8]);
#pragma unroll
        for (int mt = 0; mt < 4; ++mt)
#pragma unroll
            for (int nt = 0; nt < 4; ++nt)
                acc[mt][nt] = __builtin_amdgcn_mfma_f32_16x16x32_f16(
                    afr[mt], bfr[nt], acc[mt][nt], 0, 0, 0);
    }

    float pqv[4], vv[4];
#pragma unroll
    for (int nt = 0; nt < 4; ++nt) {
        int ug = bn * 128 + wn * 64 + nt * 16 + l16;
        pqv[nt] = pq[(size_t)n * DIM + ug];
        vv[nt]  = v[ug];
    }
#pragma unroll
    for (int mt = 0; mt < 4; ++mt) {
#pragma unroll
        for (int r = 0; r < 4; ++r) {
            float s = 0.f;
#pragma unroll
            for (int nt = 0; nt < 4; ++nt)
                s += ftanh(acc[mt][nt][r] + pqv[nt]) * vv[nt];
            s += __shfl_xor(s, 1);
            s += __shfl_xor(s, 2);
            s += __shfl_xor(s, 4);
            s += __shfl_xor(s, 8);
            if (l16 == 0) {
                int R = rowBase + wm * 64 + mt * 16 + q4 * 4 + r;
                atomicAdd(&weights[R], s);
            }
        }
    }
}

// ---------------- K2 (fallback): inline-convert f32 GEMM (round-1) ----------------
__global__ __launch_bounds__(256) void gemm_tanh_kernel(
        const float* __restrict__ enc, const float* __restrict__ Wk,
        const float* __restrict__ pq,  const float* __restrict__ v,
        const int* __restrict__ lengths, float* __restrict__ weights) {
    const int bm = blockIdx.x;
    const int bn = blockIdx.y;
    const int rowBase = bm * 128;
    const int n = rowBase >> 11;
    const int tstart = rowBase & 2047;
    if (lengths[n] <= tstart) return;

    __shared__ _Float16 As[128 * 40];
    __shared__ _Float16 Bs[128 * 40];

    const int tid  = threadIdx.x;
    const int lane = tid & 63;
    const int wv   = tid >> 6;
    const int wm   = wv >> 1, wn = wv & 1;
    const int q4   = lane >> 4;
    const int l16  = lane & 15;

    v4f acc[4][4];
    const v4f vz = {0.f, 0.f, 0.f, 0.f};
#pragma unroll
    for (int i = 0; i < 4; ++i)
#pragma unroll
        for (int j = 0; j < 4; ++j) acc[i][j] = vz;

    const int srow = tid >> 3;
    const int skc  = (tid & 7) * 4;

    for (int k0 = 0; k0 < DIM; k0 += 32) {
        __syncthreads();
#pragma unroll
        for (int j = 0; j < 4; ++j) {
            int row = j * 32 + srow;
            float4 av = *(const float4*)(enc + (size_t)(rowBase + row) * DIM + k0 + skc);
            v4h ah;
            ah.x = (_Float16)av.x; ah.y = (_Float16)av.y;
            ah.z = (_Float16)av.z; ah.w = (_Float16)av.w;
            *(v4h*)(&As[row * 40 + skc]) = ah;
            float4 bv = *(const float4*)(Wk + (size_t)(bn * 128 + row) * DIM + k0 + skc);
            v4h bh;
            bh.x = (_Float16)bv.x; bh.y = (_Float16)bv.y;
            bh.z = (_Float16)bv.z; bh.w = (_Float16)bv.w;
            *(v4h*)(&Bs[row * 40 + skc]) = bh;
        }
        __syncthreads();

        v8h afr[4], bfr[4];
#pragma unroll
        for (int mt = 0; mt < 4; ++mt)
            afr[mt] = *(const v8h*)(&As[(wm * 64 + mt * 16 + l16) * 40 + q4 * 8]);
#pragma unroll
        for (int nt = 0; nt < 4; ++nt)
            bfr[nt] = *(const v8h*)(&Bs[(wn * 64 + nt * 16 + l16) * 40 + q4 * 8]);
#pragma unroll
        for (int mt = 0; mt < 4; ++mt)
#pragma unroll
            for (int nt = 0; nt < 4; ++nt)
                acc[mt][nt] = __builtin_amdgcn_mfma_f32_16x16x32_f16(
                    afr[mt], bfr[nt], acc[mt][nt], 0, 0, 0);
    }

    float pqv[4], vv[4];
#pragma unroll
    for (int nt = 0; nt < 4; ++nt) {
        int ug = bn * 128 + wn * 64 + nt * 16 + l16;
        pqv[nt] = pq[(size_t)n * DIM + ug];
        vv[nt]  = v[ug];
    }
#pragma unroll
    for (int mt = 0; mt < 4; ++mt) {
#pragma unroll
        for (int r = 0; r < 4; ++r) {
            float s = 0.f;
#pragma unroll
            for (int nt = 0; nt < 4; ++nt)
                s += ftanh(acc[mt][nt][r] + pqv[nt]) * vv[nt];
            s += __shfl_xor(s, 1);
            s += __shfl_xor(s, 2);
            s += __shfl_xor(s, 4);
            s += __shfl_xor(s, 8);
            if (l16 == 0) {
                int R = rowBase + wm * 64 + mt * 16 + q4 * 4 + r;
                atomicAdd(&weights[R], s);
            }
        }
    }
}

// ---------------- K3: masked softmax per n-row, in place ----------------
__global__ __launch_bounds__(256) void softmax_kernel(float* __restrict__ w,
                                                      const int* __restrict__ lengths) {
    int n = blockIdx.x;
    int len = lengths[n];
    float* row = w + (size_t)n * TD;
    int tid = threadIdx.x;
    float wv[8], ev[8];
    float mx = -INFINITY;
#pragma unroll
    for (int i = 0; i < 8; ++i) {
        int t = tid + i * 256;
        float x = row[t];
        x = (t < len) ? x : -INFINITY;
        wv[i] = x;
        mx = fmaxf(mx, x);
    }
#pragma unroll
    for (int off = 32; off >= 1; off >>= 1) mx = fmaxf(mx, __shfl_xor(mx, off));
    __shared__ float redm[4], reds[4];
    int lane = tid & 63, wvid = tid >> 6;
    if (lane == 0) redm[wvid] = mx;
    __syncthreads();
    mx = fmaxf(fmaxf(redm[0], redm[1]), fmaxf(redm[2], redm[3]));
    float sm = 0.f;
#pragma unroll
    for (int i = 0; i < 8; ++i) { ev[i] = __expf(wv[i] - mx); sm += ev[i]; }
#pragma unroll
    for (int off = 32; off >= 1; off >>= 1) sm += __shfl_xor(sm, off);
    if (lane == 0) reds[wvid] = sm;
    __syncthreads();
    sm = reds[0] + reds[1] + reds[2] + reds[3];
    float inv = 1.f / sm;
#pragma unroll
    for (int i = 0; i < 8; ++i) row[tid + i * 256] = ev[i] * inv;
}

// ---------------- K4 (fast): contexts from f16 enc, t-chunks of 32 ----------------
__global__ __launch_bounds__(256) void ctx_kernel_h(const float* __restrict__ align,
                                                    const _Float16* __restrict__ ench,
                                                    const int* __restrict__ lengths,
                                                    float* __restrict__ ctx) {
    int n  = blockIdx.y;
    int t0 = blockIdx.x * 32;
    int len = lengths[n];
    if (len <= t0) return;
    int e = threadIdx.x * 4;
    float4 acc = make_float4(0.f, 0.f, 0.f, 0.f);
    const float* arow = align + (size_t)n * TD;
    const _Float16* erow = ench + (size_t)n * TD * DIM;
    int tend = min(t0 + 32, len);   // only converted (valid) rows
    for (int t = t0; t < tend; ++t) {
        float a = arow[t];
        v4h ev = *(const v4h*)(erow + (size_t)t * DIM + e);
        acc.x += a * (float)ev[0]; acc.y += a * (float)ev[1];
        acc.z += a * (float)ev[2]; acc.w += a * (float)ev[3];
    }
    float* c = ctx + (size_t)n * DIM + e;
    atomicAdd(c + 0, acc.x);
    atomicAdd(c + 1, acc.y);
    atomicAdd(c + 2, acc.z);
    atomicAdd(c + 3, acc.w);
}

// ---------------- K4 (fallback): f32 enc ----------------
__global__ __launch_bounds__(256) void ctx_kernel(const float* __restrict__ align,
                                                  const float* __restrict__ enc,
                                                  const int* __restrict__ lengths,
                                                  float* __restrict__ ctx) {
    int n  = blockIdx.y;
    int t0 = blockIdx.x * 128;
    if (lengths[n] <= t0) return;
    int e = threadIdx.x * 4;
    float4 acc = make_float4(0.f, 0.f, 0.f, 0.f);
    const float* arow = align + (size_t)n * TD;
    const float* erow = enc + (size_t)n * TD * DIM;
    for (int tt = 0; tt < 128; ++tt) {
        int t = t0 + tt;
        float a = arow[t];
        if (a != 0.f) {
            float4 evv = *(const float4*)(erow + (size_t)t * DIM + e);
            acc.x += a * evv.x; acc.y += a * evv.y;
            acc.z += a * evv.z; acc.w += a * evv.w;
        }
    }
    float* c = ctx + (size_t)n * DIM + e;
    atomicAdd(c + 0, acc.x);
    atomicAdd(c + 1, acc.y);
    atomicAdd(c + 2, acc.z);
    atomicAdd(c + 3, acc.w);
}

extern "C" void kernel_launch(void* const* d_in, const int* in_sizes, int n_in,
                              void* d_out, int out_size, void* d_ws, size_t ws_size,
                              hipStream_t stream) {
    const float* queries = (const float*)d_in[0];   // [32,1,1024]
    const float* enc     = (const float*)d_in[1];   // [32,2048,1024]
    const int*   lengths = (const int*)d_in[2];     // [32]
    const float* v       = (const float*)d_in[3];   // [1024]
    const float* Wq      = (const float*)d_in[4];   // [1024,1024]
    const float* Wk      = (const float*)d_in[5];   // [1024,1024]

    float* out = (float*)d_out;
    float* ctx = out;                // [32,1024]  (also temp home of pq)
    float* alg = out + NB * DIM;     // [32,2048]  (weights -> alignments in place)
    float* pq  = ctx;                // pq fully consumed before ctx memset below
    (void)in_sizes; (void)n_in; (void)out_size;

    const size_t ench_elems = (size_t)NB * TD * DIM;
    const size_t need = (ench_elems + (size_t)DIM * DIM) * sizeof(_Float16);

    hipMemsetAsync(alg, 0, (size_t)NB * TD * sizeof(float), stream);
    pq_kernel<<<NB * DIM / 4, 256, 0, stream>>>(queries, Wq, pq);

    if (ws_size >= need) {
        _Float16* ench = (_Float16*)d_ws;
        _Float16* wkh  = ench + ench_elems;
        cvt_kernel<<<32768 + 512, 256, 0, stream>>>(enc, Wk, lengths, ench, wkh);
        dim3 g2(512, 8);
        gemm_tanh_h<<<g2, 256, 0, stream>>>(ench, wkh, pq, v, lengths, alg);
        softmax_kernel<<<NB, 256, 0, stream>>>(alg, lengths);
        hipMemsetAsync(ctx, 0, (size_t)NB * DIM * sizeof(float), stream);
        ctx_kernel_h<<<dim3(64, NB), 256, 0, stream>>>(alg, ench, lengths, ctx);
    } else {
        dim3 g2(512, 8);
        gemm_tanh_kernel<<<g2, 256, 0, stream>>>(enc, Wk, pq, v, lengths, alg);
        softmax_kernel<<<NB, 256, 0, stream>>>(alg, lengths);
        hipMemsetAsync(ctx, 0, (size_t)NB * DIM * sizeof(float), stream);
        ctx_kernel<<<dim3(16, NB), 256, 0, stream>>>(alg, enc, lengths, ctx);
    }
}